// Round 6
// baseline (628.940 us; speedup 1.0000x reference)
//
#include <hip/hip_runtime.h>
#include <math.h>

#define N_NODES 50000
#define N_EDGES 1200000
#define IN_DIM  256
#define OUT_DIM 64
#define SLOPE   0.2f
#define BNODES  64           // nodes per bucket: b = dst>>6, dl = dst&63
#define NBKT    782          // ceil(50000/64)
#define NBKT_PAD 1024
#define EPB     4096         // edges per k_bin block

typedef unsigned int   uint;
typedef unsigned short ushort;
typedef float  f32x4  __attribute__((ext_vector_type(4)));
typedef short  short8 __attribute__((ext_vector_type(8)));

__device__ inline ushort bf16_rne(float f) {
    uint u = __float_as_uint(f);
    u += 0x7FFF + ((u >> 16) & 1);
    return (ushort)(u >> 16);
}
__device__ inline float bf16_f32(ushort s) {
    return __uint_as_float(((uint)s) << 16);
}
__device__ inline ushort f32_f16(float f) {
    _Float16 h = (_Float16)f;
    return __builtin_bit_cast(ushort, h);
}
__device__ inline float f16_f32(ushort u) {
    return (float)__builtin_bit_cast(_Float16, u);
}

// ---------------------------------------------------------------------------
// K0: blocks 0..255: coarse dst histogram (1024-padded); blocks 256+: W prep
// ---------------------------------------------------------------------------
__global__ __launch_bounds__(256) void k_prep_hist(const float* __restrict__ Wfc,
                                                   ushort* __restrict__ Whi,
                                                   ushort* __restrict__ Wlo,
                                                   const int* __restrict__ dst,
                                                   int* __restrict__ gcount) {
    if (blockIdx.x >= 256) {
        int i = (blockIdx.x - 256) * 256 + threadIdx.x;
        if (i < OUT_DIM * IN_DIM) {
            float f = Wfc[i];
            ushort hi = bf16_rne(f);
            Whi[i] = hi;
            Wlo[i] = bf16_rne(f - bf16_f32(hi));
        }
        return;
    }
    __shared__ int lh[NBKT_PAD];
    int t = threadIdx.x;
    #pragma unroll
    for (int i = 0; i < NBKT_PAD / 256; ++i) lh[i * 256 + t] = 0;
    __syncthreads();
    for (int e = blockIdx.x * 256 + t; e < N_EDGES; e += 256 * 256)
        atomicAdd(&lh[dst[e] >> 6], 1);
    __syncthreads();
    #pragma unroll
    for (int i = 0; i < NBKT_PAD / 256; ++i) {
        int v = lh[i * 256 + t];
        if (v) atomicAdd(&gcount[i * 256 + t], v);
    }
}

// ---------------------------------------------------------------------------
// K1: z = h @ W^T via mfma_f32_16x16x32_bf16, split-bf16 (hihi + lohi + hilo).
// One wave / 16 nodes, no LDS. Fused sS/sD. z stored f16.
// ---------------------------------------------------------------------------
__global__ __launch_bounds__(64) void k_gemm(const float* __restrict__ h,
                                             const ushort* __restrict__ Whi,
                                             const ushort* __restrict__ Wlo,
                                             const float* __restrict__ Wattn,
                                             ushort* __restrict__ zh,
                                             float* __restrict__ sS,
                                             float* __restrict__ sD) {
    const int l   = threadIdx.x;
    const int r16 = l & 15;
    const int g   = l >> 4;
    const int base = blockIdx.x * 16;

    const float*  ha = h   + (size_t)(base + r16) * IN_DIM + g * 8;
    const ushort* wh = Whi + (size_t)r16 * IN_DIM + g * 8;
    const ushort* wl = Wlo + (size_t)r16 * IN_DIM + g * 8;

    f32x4 c[4] = {{0,0,0,0},{0,0,0,0},{0,0,0,0},{0,0,0,0}};

    #pragma unroll
    for (int ks = 0; ks < 8; ++ks) {
        float4 a0 = *(const float4*)(ha + ks * 32);
        float4 a1 = *(const float4*)(ha + ks * 32 + 4);
        float af[8] = {a0.x, a0.y, a0.z, a0.w, a1.x, a1.y, a1.z, a1.w};
        short8 ahi, alo;
        #pragma unroll
        for (int i = 0; i < 8; ++i) {
            ushort hi = bf16_rne(af[i]);
            ahi[i] = (short)hi;
            alo[i] = (short)bf16_rne(af[i] - bf16_f32(hi));
        }
        #pragma unroll
        for (int n = 0; n < 4; ++n) {
            short8 bh = *(const short8*)(wh + n * 16 * IN_DIM + ks * 32);
            short8 bl = *(const short8*)(wl + n * 16 * IN_DIM + ks * 32);
            c[n] = __builtin_amdgcn_mfma_f32_16x16x32_bf16(ahi, bh, c[n], 0, 0, 0);
            c[n] = __builtin_amdgcn_mfma_f32_16x16x32_bf16(alo, bh, c[n], 0, 0, 0);
            c[n] = __builtin_amdgcn_mfma_f32_16x16x32_bf16(ahi, bl, c[n], 0, 0, 0);
        }
    }

    float aSv[4], aDv[4];
    #pragma unroll
    for (int n = 0; n < 4; ++n) {
        aSv[n] = Wattn[n * 16 + r16];
        aDv[n] = Wattn[OUT_DIM + n * 16 + r16];
    }
    #pragma unroll
    for (int r = 0; r < 4; ++r) {
        int node = base + g * 4 + r;
        float ss = 0.f, sd = 0.f;
        #pragma unroll
        for (int n = 0; n < 4; ++n) {
            float v = c[n][r];
            zh[(size_t)node * OUT_DIM + n * 16 + r16] = f32_f16(v);
            ss += v * aSv[n];
            sd += v * aDv[n];
        }
        ss += __shfl_xor(ss, 1); ss += __shfl_xor(ss, 2);
        ss += __shfl_xor(ss, 4); ss += __shfl_xor(ss, 8);
        sd += __shfl_xor(sd, 1); sd += __shfl_xor(sd, 2);
        sd += __shfl_xor(sd, 4); sd += __shfl_xor(sd, 8);
        if (r16 == 0) { sS[node] = ss; sD[node] = sd; }
    }
}

// ---------------------------------------------------------------------------
// K2: scan 1024 counts -> bucketPtr[1025]; bucketCur = bucketPtr (4/thread)
// ---------------------------------------------------------------------------
__global__ __launch_bounds__(256) void k_scan(const int* __restrict__ gcount,
                                              int* __restrict__ bucketPtr,
                                              int* __restrict__ bucketCur) {
    __shared__ int ws[256];
    int t = threadIdx.x;
    int4 v = ((const int4*)gcount)[t];
    int lsum = v.x + v.y + v.z + v.w;
    ws[t] = lsum; __syncthreads();
    for (int off = 1; off < 256; off <<= 1) {
        int x = (t >= off) ? ws[t - off] : 0;
        __syncthreads(); ws[t] += x; __syncthreads();
    }
    int excl = ws[t] - lsum;
    int4 p;
    p.x = excl;
    p.y = p.x + v.x;
    p.z = p.y + v.y;
    p.w = p.z + v.z;
    ((int4*)bucketPtr)[t] = p;
    ((int4*)bucketCur)[t] = p;
    if (t == 255) bucketPtr[NBKT_PAD] = N_EDGES;
}

// ---------------------------------------------------------------------------
// K3: LDS-staged multisplit into 782 buckets. pack = (b<<22)|(dl<<16)|src.
// ---------------------------------------------------------------------------
__global__ __launch_bounds__(256) void k_bin(const int* __restrict__ src,
                                             const int* __restrict__ dst,
                                             int* __restrict__ bucketCur,
                                             uint* __restrict__ binned) {
    __shared__ uint staged[EPB];
    __shared__ int lhist[NBKT_PAD], lscan[NBKT_PAD], lcur[NBKT_PAD], gbase[NBKT_PAD];
    __shared__ int ws[256];
    int t = threadIdx.x;
    int base = blockIdx.x * EPB;
    int n = min(EPB, N_EDGES - base);
    ((int4*)lhist)[t] = int4{0, 0, 0, 0};
    __syncthreads();
    #pragma unroll
    for (int k = 0; k < EPB / 256; ++k) {
        int i = k * 256 + t;
        if (i < n) atomicAdd(&lhist[dst[base + i] >> 6], 1);
    }
    __syncthreads();
    int4 hv = ((const int4*)lhist)[t];
    int lsum = hv.x + hv.y + hv.z + hv.w;
    ws[t] = lsum; __syncthreads();
    for (int off = 1; off < 256; off <<= 1) {
        int x = (t >= off) ? ws[t - off] : 0;
        __syncthreads(); ws[t] += x; __syncthreads();
    }
    int excl = ws[t] - lsum;
    int p0 = excl, p1 = p0 + hv.x, p2 = p1 + hv.y, p3 = p2 + hv.z;
    lscan[4 * t]     = p0; lcur[4 * t]     = p0;
    lscan[4 * t + 1] = p1; lcur[4 * t + 1] = p1;
    lscan[4 * t + 2] = p2; lcur[4 * t + 2] = p2;
    lscan[4 * t + 3] = p3; lcur[4 * t + 3] = p3;
    gbase[4 * t]     = hv.x ? atomicAdd(&bucketCur[4 * t],     hv.x) : 0;
    gbase[4 * t + 1] = hv.y ? atomicAdd(&bucketCur[4 * t + 1], hv.y) : 0;
    gbase[4 * t + 2] = hv.z ? atomicAdd(&bucketCur[4 * t + 2], hv.z) : 0;
    gbase[4 * t + 3] = hv.w ? atomicAdd(&bucketCur[4 * t + 3], hv.w) : 0;
    __syncthreads();
    #pragma unroll
    for (int k = 0; k < EPB / 256; ++k) {
        int i = k * 256 + t;
        if (i < n) {
            int d = dst[base + i], s = src[base + i];
            int b = d >> 6, dl = d & 63;
            int slot = atomicAdd(&lcur[b], 1);
            staged[slot] = ((uint)b << 22) | ((uint)dl << 16) | (uint)s;
        }
    }
    __syncthreads();
    #pragma unroll
    for (int k = 0; k < EPB / 256; ++k) {
        int i = k * 256 + t;
        if (i < n) {
            uint w = staged[i];
            int b = (int)(w >> 22);
            binned[gbase[b] + (i - lscan[b])] = w;
        }
    }
}

// ---------------------------------------------------------------------------
// K4: fused segment-softmax + aggregation. One block per 64-node bucket:
// stream binned edges once; acc[dl][lane] += exp(leaky(sS[s]+sD[d]))*z[s][lane]
// via LDS f32 atomics (2-lane/bank: conflict-free); denom in LDS; ELU write.
// ---------------------------------------------------------------------------
__global__ __launch_bounds__(256) void k_agg(const uint* __restrict__ binned,
                                             const int* __restrict__ bucketPtr,
                                             const float* __restrict__ sS,
                                             const float* __restrict__ sD,
                                             const ushort* __restrict__ zh,
                                             float* __restrict__ out) {
    __shared__ float acc[BNODES * 64];    // 16 KB
    __shared__ float lden[BNODES];
    __shared__ float ldsD[BNODES];
    int b = blockIdx.x, t = threadIdx.x;
    int nodeBase = b << 6;
    #pragma unroll
    for (int i = 0; i < (BNODES * 64) / 256; ++i) acc[i * 256 + t] = 0.f;
    if (t < BNODES) {
        int nd = nodeBase + t;
        ldsD[t] = (nd < N_NODES) ? sD[nd] : 0.f;
        lden[t] = 0.f;
    }
    __syncthreads();

    int beg = bucketPtr[b], end = bucketPtr[b + 1];
    int lane = t & 63, wid = t >> 6;
    int cnt = end - beg;
    int q = (cnt + 3) >> 2;
    int wbeg = beg + wid * q;
    int wend = min(wbeg + q, end);

    int k = wbeg;
    for (; k + 8 <= wend; k += 8) {
        uint w[8];
        #pragma unroll
        for (int u = 0; u < 8; ++u) w[u] = binned[k + u];
        float z[8], e[8];
        #pragma unroll
        for (int u = 0; u < 8; ++u) {
            int s = (int)(w[u] & 0xFFFF);
            z[u] = f16_f32(zh[(s << 6) + lane]);
        }
        #pragma unroll
        for (int u = 0; u < 8; ++u) {
            float sc = sS[w[u] & 0xFFFF] + ldsD[(w[u] >> 16) & 63];
            sc = sc > 0.f ? sc : SLOPE * sc;
            e[u] = __expf(sc);
        }
        #pragma unroll
        for (int u = 0; u < 8; ++u)
            atomicAdd(&acc[(((w[u] >> 16) & 63) << 6) + lane], e[u] * z[u]);
        if (lane == 0) {
            #pragma unroll
            for (int u = 0; u < 8; ++u)
                atomicAdd(&lden[(w[u] >> 16) & 63], e[u]);
        }
    }
    for (; k < wend; ++k) {
        uint w = binned[k];
        int s = (int)(w & 0xFFFF), dl = (int)((w >> 16) & 63);
        float sc = sS[s] + ldsD[dl];
        sc = sc > 0.f ? sc : SLOPE * sc;
        float ex = __expf(sc);
        float z = f16_f32(zh[(s << 6) + lane]);
        atomicAdd(&acc[(dl << 6) + lane], ex * z);
        if (lane == 0) atomicAdd(&lden[dl], ex);
    }
    __syncthreads();

    #pragma unroll
    for (int i = 0; i < (BNODES * 64) / 256; ++i) {
        int idx = i * 256 + t;
        int node = nodeBase + (idx >> 6);
        if (node < N_NODES) {
            float den = lden[idx >> 6];
            float r = den > 0.f ? acc[idx] / den : 0.f;
            out[(((size_t)nodeBase) << 6) + idx] = r > 0.f ? r : expm1f(r);
        }
    }
}

static inline char* alignup(char* p) {
    return (char*)(((uintptr_t)p + 63) & ~(uintptr_t)63);
}

extern "C" void kernel_launch(void* const* d_in, const int* in_sizes, int n_in,
                              void* d_out, int out_size, void* d_ws, size_t ws_size,
                              hipStream_t stream) {
    const float* h     = (const float*)d_in[0];
    const float* Wfc   = (const float*)d_in[1];
    const float* Wattn = (const float*)d_in[2];
    const int*   src   = (const int*)d_in[3];
    const int*   dst   = (const int*)d_in[4];
    float* out = (float*)d_out;

    // workspace layout (64B-aligned regions)
    char* p = (char*)d_ws;
    uint*   binned    = (uint*)p;             p = alignup(p + (size_t)N_EDGES * 4);
    float*  sS        = (float*)p;            p = alignup(p + (size_t)N_NODES * 4);
    float*  sD        = (float*)p;            p = alignup(p + (size_t)N_NODES * 4);
    int*    gcount    = (int*)p;              p = alignup(p + NBKT_PAD * 4);
    int*    bucketPtr = (int*)p;              p = alignup(p + (NBKT_PAD + 1) * 4);
    int*    bucketCur = (int*)p;              p = alignup(p + NBKT_PAD * 4);
    ushort* Whi       = (ushort*)p;           p = alignup(p + OUT_DIM * IN_DIM * 2);
    ushort* Wlo       = (ushort*)p;           p = alignup(p + OUT_DIM * IN_DIM * 2);
    ushort* zh        = (ushort*)p;

    hipMemsetAsync(gcount, 0, NBKT_PAD * sizeof(int), stream);

    k_prep_hist<<<256 + 64, 256, 0, stream>>>(Wfc, Whi, Wlo, dst, gcount);
    k_gemm<<<N_NODES / 16, 64, 0, stream>>>(h, Whi, Wlo, Wattn, zh, sS, sD);
    k_scan<<<1, 256, 0, stream>>>(gcount, bucketPtr, bucketCur);
    k_bin<<<(N_EDGES + EPB - 1) / EPB, 256, 0, stream>>>(src, dst, bucketCur, binned);
    k_agg<<<NBKT, 256, 0, stream>>>(binned, bucketPtr, sS, sD, zh, out);
}

// Round 7
// 184.799 us; speedup vs baseline: 3.4034x; 3.4034x over previous
//
#include <hip/hip_runtime.h>
#include <math.h>

#define N_NODES 50000
#define N_EDGES 1200000
#define IN_DIM  256
#define OUT_DIM 64
#define SLOPE   0.2f
#define BNODES  64           // nodes per bucket: b = dst>>6, dl = dst&63
#define NBKT    782          // ceil(50000/64)
#define NBKT_PAD 1024
#define EPB     4096         // edges per k_bin block
#define BCAP    2048         // max edges per bucket (mean 1536, +13 sigma)

typedef unsigned int   uint;
typedef unsigned short ushort;
typedef float  f32x4  __attribute__((ext_vector_type(4)));
typedef short  short8 __attribute__((ext_vector_type(8)));

__device__ inline ushort bf16_rne(float f) {
    uint u = __float_as_uint(f);
    u += 0x7FFF + ((u >> 16) & 1);
    return (ushort)(u >> 16);
}
__device__ inline float bf16_f32(ushort s) {
    return __uint_as_float(((uint)s) << 16);
}
__device__ inline ushort f32_f16(float f) {
    _Float16 h = (_Float16)f;
    return __builtin_bit_cast(ushort, h);
}
__device__ inline float f16_f32(ushort u) {
    return (float)__builtin_bit_cast(_Float16, u);
}

// ---------------------------------------------------------------------------
// K0: blocks 0..255: coarse dst histogram (1024-padded); blocks 256+: W prep
// ---------------------------------------------------------------------------
__global__ __launch_bounds__(256) void k_prep_hist(const float* __restrict__ Wfc,
                                                   ushort* __restrict__ Whi,
                                                   ushort* __restrict__ Wlo,
                                                   const int* __restrict__ dst,
                                                   int* __restrict__ gcount) {
    if (blockIdx.x >= 256) {
        int i = (blockIdx.x - 256) * 256 + threadIdx.x;
        if (i < OUT_DIM * IN_DIM) {
            float f = Wfc[i];
            ushort hi = bf16_rne(f);
            Whi[i] = hi;
            Wlo[i] = bf16_rne(f - bf16_f32(hi));
        }
        return;
    }
    __shared__ int lh[NBKT_PAD];
    int t = threadIdx.x;
    #pragma unroll
    for (int i = 0; i < NBKT_PAD / 256; ++i) lh[i * 256 + t] = 0;
    __syncthreads();
    for (int e = blockIdx.x * 256 + t; e < N_EDGES; e += 256 * 256)
        atomicAdd(&lh[dst[e] >> 6], 1);
    __syncthreads();
    #pragma unroll
    for (int i = 0; i < NBKT_PAD / 256; ++i) {
        int v = lh[i * 256 + t];
        if (v) atomicAdd(&gcount[i * 256 + t], v);
    }
}

// ---------------------------------------------------------------------------
// K1: z = h @ W^T via mfma_f32_16x16x32_bf16, split-bf16 (hihi + lohi + hilo).
// One wave / 16 nodes, no LDS. Fused sS/sD. z stored f16.
// ---------------------------------------------------------------------------
__global__ __launch_bounds__(64) void k_gemm(const float* __restrict__ h,
                                             const ushort* __restrict__ Whi,
                                             const ushort* __restrict__ Wlo,
                                             const float* __restrict__ Wattn,
                                             ushort* __restrict__ zh,
                                             float* __restrict__ sS,
                                             float* __restrict__ sD) {
    const int l   = threadIdx.x;
    const int r16 = l & 15;
    const int g   = l >> 4;
    const int base = blockIdx.x * 16;

    const float*  ha = h   + (size_t)(base + r16) * IN_DIM + g * 8;
    const ushort* wh = Whi + (size_t)r16 * IN_DIM + g * 8;
    const ushort* wl = Wlo + (size_t)r16 * IN_DIM + g * 8;

    f32x4 c[4] = {{0,0,0,0},{0,0,0,0},{0,0,0,0},{0,0,0,0}};

    #pragma unroll
    for (int ks = 0; ks < 8; ++ks) {
        float4 a0 = *(const float4*)(ha + ks * 32);
        float4 a1 = *(const float4*)(ha + ks * 32 + 4);
        float af[8] = {a0.x, a0.y, a0.z, a0.w, a1.x, a1.y, a1.z, a1.w};
        short8 ahi, alo;
        #pragma unroll
        for (int i = 0; i < 8; ++i) {
            ushort hi = bf16_rne(af[i]);
            ahi[i] = (short)hi;
            alo[i] = (short)bf16_rne(af[i] - bf16_f32(hi));
        }
        #pragma unroll
        for (int n = 0; n < 4; ++n) {
            short8 bh = *(const short8*)(wh + n * 16 * IN_DIM + ks * 32);
            short8 bl = *(const short8*)(wl + n * 16 * IN_DIM + ks * 32);
            c[n] = __builtin_amdgcn_mfma_f32_16x16x32_bf16(ahi, bh, c[n], 0, 0, 0);
            c[n] = __builtin_amdgcn_mfma_f32_16x16x32_bf16(alo, bh, c[n], 0, 0, 0);
            c[n] = __builtin_amdgcn_mfma_f32_16x16x32_bf16(ahi, bl, c[n], 0, 0, 0);
        }
    }

    float aSv[4], aDv[4];
    #pragma unroll
    for (int n = 0; n < 4; ++n) {
        aSv[n] = Wattn[n * 16 + r16];
        aDv[n] = Wattn[OUT_DIM + n * 16 + r16];
    }
    #pragma unroll
    for (int r = 0; r < 4; ++r) {
        int node = base + g * 4 + r;
        float ss = 0.f, sd = 0.f;
        #pragma unroll
        for (int n = 0; n < 4; ++n) {
            float v = c[n][r];
            zh[(size_t)node * OUT_DIM + n * 16 + r16] = f32_f16(v);
            ss += v * aSv[n];
            sd += v * aDv[n];
        }
        ss += __shfl_xor(ss, 1); ss += __shfl_xor(ss, 2);
        ss += __shfl_xor(ss, 4); ss += __shfl_xor(ss, 8);
        sd += __shfl_xor(sd, 1); sd += __shfl_xor(sd, 2);
        sd += __shfl_xor(sd, 4); sd += __shfl_xor(sd, 8);
        if (r16 == 0) { sS[node] = ss; sD[node] = sd; }
    }
}

// ---------------------------------------------------------------------------
// K2: scan 1024 counts -> bucketPtr[1025]; bucketCur = bucketPtr (4/thread)
// ---------------------------------------------------------------------------
__global__ __launch_bounds__(256) void k_scan(const int* __restrict__ gcount,
                                              int* __restrict__ bucketPtr,
                                              int* __restrict__ bucketCur) {
    __shared__ int ws[256];
    int t = threadIdx.x;
    int4 v = ((const int4*)gcount)[t];
    int lsum = v.x + v.y + v.z + v.w;
    ws[t] = lsum; __syncthreads();
    for (int off = 1; off < 256; off <<= 1) {
        int x = (t >= off) ? ws[t - off] : 0;
        __syncthreads(); ws[t] += x; __syncthreads();
    }
    int excl = ws[t] - lsum;
    int4 p;
    p.x = excl;
    p.y = p.x + v.x;
    p.z = p.y + v.y;
    p.w = p.z + v.z;
    ((int4*)bucketPtr)[t] = p;
    ((int4*)bucketCur)[t] = p;
    if (t == 255) bucketPtr[NBKT_PAD] = N_EDGES;
}

// ---------------------------------------------------------------------------
// K3: LDS-staged multisplit into 782 buckets. pack = (b<<22)|(dl<<16)|src.
// ---------------------------------------------------------------------------
__global__ __launch_bounds__(256) void k_bin(const int* __restrict__ src,
                                             const int* __restrict__ dst,
                                             int* __restrict__ bucketCur,
                                             uint* __restrict__ binned) {
    __shared__ uint staged[EPB];
    __shared__ int lhist[NBKT_PAD], lscan[NBKT_PAD], lcur[NBKT_PAD], gbase[NBKT_PAD];
    __shared__ int ws[256];
    int t = threadIdx.x;
    int base = blockIdx.x * EPB;
    int n = min(EPB, N_EDGES - base);
    ((int4*)lhist)[t] = int4{0, 0, 0, 0};
    __syncthreads();
    #pragma unroll
    for (int k = 0; k < EPB / 256; ++k) {
        int i = k * 256 + t;
        if (i < n) atomicAdd(&lhist[dst[base + i] >> 6], 1);
    }
    __syncthreads();
    int4 hv = ((const int4*)lhist)[t];
    int lsum = hv.x + hv.y + hv.z + hv.w;
    ws[t] = lsum; __syncthreads();
    for (int off = 1; off < 256; off <<= 1) {
        int x = (t >= off) ? ws[t - off] : 0;
        __syncthreads(); ws[t] += x; __syncthreads();
    }
    int excl = ws[t] - lsum;
    int p0 = excl, p1 = p0 + hv.x, p2 = p1 + hv.y, p3 = p2 + hv.z;
    lscan[4 * t]     = p0; lcur[4 * t]     = p0;
    lscan[4 * t + 1] = p1; lcur[4 * t + 1] = p1;
    lscan[4 * t + 2] = p2; lcur[4 * t + 2] = p2;
    lscan[4 * t + 3] = p3; lcur[4 * t + 3] = p3;
    gbase[4 * t]     = hv.x ? atomicAdd(&bucketCur[4 * t],     hv.x) : 0;
    gbase[4 * t + 1] = hv.y ? atomicAdd(&bucketCur[4 * t + 1], hv.y) : 0;
    gbase[4 * t + 2] = hv.z ? atomicAdd(&bucketCur[4 * t + 2], hv.z) : 0;
    gbase[4 * t + 3] = hv.w ? atomicAdd(&bucketCur[4 * t + 3], hv.w) : 0;
    __syncthreads();
    #pragma unroll
    for (int k = 0; k < EPB / 256; ++k) {
        int i = k * 256 + t;
        if (i < n) {
            int d = dst[base + i], s = src[base + i];
            int b = d >> 6, dl = d & 63;
            int slot = atomicAdd(&lcur[b], 1);
            staged[slot] = ((uint)b << 22) | ((uint)dl << 16) | (uint)s;
        }
    }
    __syncthreads();
    #pragma unroll
    for (int k = 0; k < EPB / 256; ++k) {
        int i = k * 256 + t;
        if (i < n) {
            uint w = staged[i];
            int b = (int)(w >> 22);
            binned[gbase[b] + (i - lscan[b])] = w;
        }
    }
}

// ---------------------------------------------------------------------------
// K4: per-64-node-bucket: LDS counting sort (slot-alloc atomics only) with
// fused score computation, then REGISTER aggregation: wave owns 16 nodes as
// 8 pairs (half-wave per node, lane = 2 output dims via packed f16 gather),
// den accumulated redundantly per lane, fused ELU + float2 store.
// ---------------------------------------------------------------------------
__global__ __launch_bounds__(256) void k_sortagg(const uint* __restrict__ binned,
                                                 const int* __restrict__ bucketPtr,
                                                 const float* __restrict__ sS,
                                                 const float* __restrict__ sD,
                                                 const uint* __restrict__ zh32,
                                                 float* __restrict__ out) {
    __shared__ uint lEdge[BCAP];            // (src<<16)|ex_f16, grouped by dl
    __shared__ int lhist[BNODES], lscan[BNODES], lcur[BNODES];
    __shared__ float ldsD[BNODES];
    __shared__ int ws[BNODES];
    int b = blockIdx.x, t = threadIdx.x;
    int nodeBase = b << 6;
    if (t < BNODES) {
        int nd = nodeBase + t;
        lhist[t] = 0;
        ldsD[t] = (nd < N_NODES) ? sD[nd] : 0.f;
    }
    __syncthreads();
    int beg = bucketPtr[b], end = bucketPtr[b + 1], n = end - beg;

    for (int i = t; i < n; i += 256)
        atomicAdd(&lhist[(binned[beg + i] >> 16) & 63], 1);
    __syncthreads();
    if (t < BNODES) ws[t] = lhist[t];
    __syncthreads();
    #pragma unroll
    for (int off = 1; off < BNODES; off <<= 1) {
        int x = 0;
        if (t < BNODES && t >= off) x = ws[t - off];
        __syncthreads();
        if (t < BNODES) ws[t] += x;
        __syncthreads();
    }
    if (t < BNODES) {
        int e = ws[t] - lhist[t];
        lscan[t] = e;
        lcur[t] = e;
    }
    __syncthreads();

    // permute + score (ex computed once per edge, f16-rounded)
    for (int i = t; i < n; i += 256) {
        uint w = binned[beg + i];
        int dl = (int)((w >> 16) & 63);
        int s  = (int)(w & 0xFFFF);
        float sc = sS[s] + ldsD[dl];
        sc = sc > 0.f ? sc : SLOPE * sc;
        ushort exh = f32_f16(__expf(sc));
        int slot = atomicAdd(&lcur[dl], 1);
        lEdge[slot] = ((w & 0xFFFFu) << 16) | (uint)exh;
    }
    __syncthreads();

    // register aggregation: wave wid -> nodes [wid*16, wid*16+16)
    int lane = t & 63, wid = t >> 6;
    int half = lane >> 5, pl = lane & 31;
    #pragma unroll
    for (int p = 0; p < 8; ++p) {
        int nlA = wid * 16 + p * 2;
        int nl  = nlA + half;
        int cnt = lhist[nl];
        int sbeg = lscan[nl];
        int trip = max(lhist[nlA], lhist[nlA + 1]);
        float acc0 = 0.f, acc1 = 0.f, den = 0.f;
        for (int i = 0; i < trip; ++i) {
            if (i < cnt) {
                uint w = lEdge[sbeg + i];                 // broadcast within half
                int s = (int)(w >> 16);
                float ex = f16_f32((ushort)(w & 0xFFFF));
                uint zp = zh32[(s << 5) + pl];            // 2 packed f16 dims
                acc0 += ex * f16_f32((ushort)(zp & 0xFFFF));
                acc1 += ex * f16_f32((ushort)(zp >> 16));
                den  += ex;
            }
        }
        int node = nodeBase + nl;
        if (node < N_NODES) {
            float r0 = den > 0.f ? acc0 / den : 0.f;
            float r1 = den > 0.f ? acc1 / den : 0.f;
            r0 = r0 > 0.f ? r0 : expm1f(r0);
            r1 = r1 > 0.f ? r1 : expm1f(r1);
            ((float2*)out)[(((size_t)node) << 5) + pl] = make_float2(r0, r1);
        }
    }
}

static inline char* alignup(char* p) {
    return (char*)(((uintptr_t)p + 63) & ~(uintptr_t)63);
}

extern "C" void kernel_launch(void* const* d_in, const int* in_sizes, int n_in,
                              void* d_out, int out_size, void* d_ws, size_t ws_size,
                              hipStream_t stream) {
    const float* h     = (const float*)d_in[0];
    const float* Wfc   = (const float*)d_in[1];
    const float* Wattn = (const float*)d_in[2];
    const int*   src   = (const int*)d_in[3];
    const int*   dst   = (const int*)d_in[4];
    float* out = (float*)d_out;

    // workspace layout (64B-aligned regions)
    char* p = (char*)d_ws;
    uint*   binned    = (uint*)p;             p = alignup(p + (size_t)N_EDGES * 4);
    float*  sS        = (float*)p;            p = alignup(p + (size_t)N_NODES * 4);
    float*  sD        = (float*)p;            p = alignup(p + (size_t)N_NODES * 4);
    int*    gcount    = (int*)p;              p = alignup(p + NBKT_PAD * 4);
    int*    bucketPtr = (int*)p;              p = alignup(p + (NBKT_PAD + 1) * 4);
    int*    bucketCur = (int*)p;              p = alignup(p + NBKT_PAD * 4);
    ushort* Whi       = (ushort*)p;           p = alignup(p + OUT_DIM * IN_DIM * 2);
    ushort* Wlo       = (ushort*)p;           p = alignup(p + OUT_DIM * IN_DIM * 2);
    ushort* zh        = (ushort*)p;

    hipMemsetAsync(gcount, 0, NBKT_PAD * sizeof(int), stream);

    k_prep_hist<<<256 + 64, 256, 0, stream>>>(Wfc, Whi, Wlo, dst, gcount);
    k_gemm<<<N_NODES / 16, 64, 0, stream>>>(h, Whi, Wlo, Wattn, zh, sS, sD);
    k_scan<<<1, 256, 0, stream>>>(gcount, bucketPtr, bucketCur);
    k_bin<<<(N_EDGES + EPB - 1) / EPB, 256, 0, stream>>>(src, dst, bucketCur, binned);
    k_sortagg<<<NBKT, 256, 0, stream>>>(binned, bucketPtr, sS, sD, (const uint*)zh, out);
}

// Round 8
// 129.141 us; speedup vs baseline: 4.8702x; 1.4310x over previous
//
#include <hip/hip_runtime.h>
#include <math.h>

#define N_NODES 50000
#define N_EDGES 1200000
#define IN_DIM  256
#define OUT_DIM 64
#define SLOPE   0.2f
#define NBKT    256          // coarse buckets, bucket = dst / 196
#define BNODES  196          // nodes per bucket (last bucket: 20)
#define EPB     4096         // edges per k_bin block
#define BCAP    5632         // max edges per bucket (mean 4704, +13.5 sigma)

typedef unsigned int   uint;
typedef unsigned short ushort;
typedef float  f32x4  __attribute__((ext_vector_type(4)));
typedef short  short8 __attribute__((ext_vector_type(8)));

__device__ inline ushort bf16_rne(float f) {
    uint u = __float_as_uint(f);
    u += 0x7FFF + ((u >> 16) & 1);
    return (ushort)(u >> 16);
}
__device__ inline float bf16_f32(ushort s) {
    return __uint_as_float(((uint)s) << 16);
}
__device__ inline ushort f32_f16(float f) {
    _Float16 h = (_Float16)f;
    return __builtin_bit_cast(ushort, h);
}
__device__ inline float f16_f32(ushort u) {
    return (float)__builtin_bit_cast(_Float16, u);
}

// ---------------------------------------------------------------------------
// K0: blocks 0..255: coarse dst histogram; blocks 256..319: W->bf16 hi/lo prep
// ---------------------------------------------------------------------------
__global__ __launch_bounds__(256) void k_prep_hist(const float* __restrict__ Wfc,
                                                   ushort* __restrict__ Whi,
                                                   ushort* __restrict__ Wlo,
                                                   const int* __restrict__ dst,
                                                   int* __restrict__ gcount) {
    if (blockIdx.x >= 256) {
        int i = (blockIdx.x - 256) * 256 + threadIdx.x;
        if (i < OUT_DIM * IN_DIM) {
            float f = Wfc[i];
            ushort hi = bf16_rne(f);
            Whi[i] = hi;
            Wlo[i] = bf16_rne(f - bf16_f32(hi));
        }
        return;
    }
    __shared__ int lh[NBKT];
    int t = threadIdx.x;
    lh[t] = 0;
    __syncthreads();
    for (int e = blockIdx.x * 256 + t; e < N_EDGES; e += 256 * 256)
        atomicAdd(&lh[dst[e] / BNODES], 1);
    __syncthreads();
    atomicAdd(&gcount[t], lh[t]);
}

// ---------------------------------------------------------------------------
// K1: z = h @ W^T via mfma_f32_16x16x32_bf16, split-bf16 (hihi + lohi + hilo).
// One wave / 16 nodes, no LDS. Fused sS/sD. z stored f16.
// ---------------------------------------------------------------------------
__global__ __launch_bounds__(64) void k_gemm(const float* __restrict__ h,
                                             const ushort* __restrict__ Whi,
                                             const ushort* __restrict__ Wlo,
                                             const float* __restrict__ Wattn,
                                             ushort* __restrict__ zh,
                                             float* __restrict__ sS,
                                             float* __restrict__ sD) {
    const int l   = threadIdx.x;
    const int r16 = l & 15;
    const int g   = l >> 4;
    const int base = blockIdx.x * 16;

    const float*  ha = h   + (size_t)(base + r16) * IN_DIM + g * 8;
    const ushort* wh = Whi + (size_t)r16 * IN_DIM + g * 8;
    const ushort* wl = Wlo + (size_t)r16 * IN_DIM + g * 8;

    f32x4 c[4] = {{0,0,0,0},{0,0,0,0},{0,0,0,0},{0,0,0,0}};

    #pragma unroll
    for (int ks = 0; ks < 8; ++ks) {
        float4 a0 = *(const float4*)(ha + ks * 32);
        float4 a1 = *(const float4*)(ha + ks * 32 + 4);
        float af[8] = {a0.x, a0.y, a0.z, a0.w, a1.x, a1.y, a1.z, a1.w};
        short8 ahi, alo;
        #pragma unroll
        for (int i = 0; i < 8; ++i) {
            ushort hi = bf16_rne(af[i]);
            ahi[i] = (short)hi;
            alo[i] = (short)bf16_rne(af[i] - bf16_f32(hi));
        }
        #pragma unroll
        for (int n = 0; n < 4; ++n) {
            short8 bh = *(const short8*)(wh + n * 16 * IN_DIM + ks * 32);
            short8 bl = *(const short8*)(wl + n * 16 * IN_DIM + ks * 32);
            c[n] = __builtin_amdgcn_mfma_f32_16x16x32_bf16(ahi, bh, c[n], 0, 0, 0);
            c[n] = __builtin_amdgcn_mfma_f32_16x16x32_bf16(alo, bh, c[n], 0, 0, 0);
            c[n] = __builtin_amdgcn_mfma_f32_16x16x32_bf16(ahi, bl, c[n], 0, 0, 0);
        }
    }

    float aSv[4], aDv[4];
    #pragma unroll
    for (int n = 0; n < 4; ++n) {
        aSv[n] = Wattn[n * 16 + r16];
        aDv[n] = Wattn[OUT_DIM + n * 16 + r16];
    }
    #pragma unroll
    for (int r = 0; r < 4; ++r) {
        int node = base + g * 4 + r;
        float ss = 0.f, sd = 0.f;
        #pragma unroll
        for (int n = 0; n < 4; ++n) {
            float v = c[n][r];
            zh[(size_t)node * OUT_DIM + n * 16 + r16] = f32_f16(v);
            ss += v * aSv[n];
            sd += v * aDv[n];
        }
        ss += __shfl_xor(ss, 1); ss += __shfl_xor(ss, 2);
        ss += __shfl_xor(ss, 4); ss += __shfl_xor(ss, 8);
        sd += __shfl_xor(sd, 1); sd += __shfl_xor(sd, 2);
        sd += __shfl_xor(sd, 4); sd += __shfl_xor(sd, 8);
        if (r16 == 0) { sS[node] = ss; sD[node] = sd; }
    }
}

// ---------------------------------------------------------------------------
// K2: scan 256 counts -> bucketPtr[257]; bucketCur = bucketPtr
// ---------------------------------------------------------------------------
__global__ __launch_bounds__(256) void k_scan(const int* __restrict__ gcount,
                                              int* __restrict__ bucketPtr,
                                              int* __restrict__ bucketCur) {
    __shared__ int sc[256];
    int t = threadIdx.x;
    int v = gcount[t];
    sc[t] = v; __syncthreads();
    for (int off = 1; off < 256; off <<= 1) {
        int x = (t >= off) ? sc[t - off] : 0;
        __syncthreads(); sc[t] += x; __syncthreads();
    }
    int excl = sc[t] - v;
    bucketPtr[t] = excl;
    bucketCur[t] = excl;
    if (t == 255) bucketPtr[256] = N_EDGES;
}

// ---------------------------------------------------------------------------
// K3: LDS-staged multisplit into 256 buckets. pack = (b<<24)|(dl<<16)|src.
// ---------------------------------------------------------------------------
__global__ __launch_bounds__(256) void k_bin(const int* __restrict__ src,
                                             const int* __restrict__ dst,
                                             int* __restrict__ bucketCur,
                                             uint* __restrict__ binned) {
    __shared__ uint staged[EPB];
    __shared__ int lhist[NBKT], lscan[NBKT], lcur[NBKT], gbaseL[NBKT], sc[NBKT];
    int t = threadIdx.x;
    int base = blockIdx.x * EPB;
    int n = min(EPB, N_EDGES - base);
    lhist[t] = 0;
    __syncthreads();
    #pragma unroll
    for (int k = 0; k < EPB / 256; ++k) {
        int i = k * 256 + t;
        if (i < n) atomicAdd(&lhist[dst[base + i] / BNODES], 1);
    }
    __syncthreads();
    int v = lhist[t]; sc[t] = v; __syncthreads();
    for (int off = 1; off < 256; off <<= 1) {
        int x = (t >= off) ? sc[t - off] : 0;
        __syncthreads(); sc[t] += x; __syncthreads();
    }
    int excl = sc[t] - v;
    lscan[t] = excl; lcur[t] = excl;
    gbaseL[t] = atomicAdd(&bucketCur[t], v);
    __syncthreads();
    #pragma unroll
    for (int k = 0; k < EPB / 256; ++k) {
        int i = k * 256 + t;
        if (i < n) {
            int d = dst[base + i], s = src[base + i];
            int b = d / BNODES, dl = d - b * BNODES;
            int slot = atomicAdd(&lcur[b], 1);
            staged[slot] = ((uint)b << 24) | ((uint)dl << 16) | (uint)s;
        }
    }
    __syncthreads();
    #pragma unroll
    for (int k = 0; k < EPB / 256; ++k) {
        int i = k * 256 + t;
        if (i < n) {
            uint w = staged[i];
            int b = (int)(w >> 24);
            binned[gbaseL[b] + (i - lscan[b])] = w;
        }
    }
}

// ---------------------------------------------------------------------------
// K4: per-bucket LDS counting sort by dst-local; computes ex=exp(leaky(.))
// per edge ONCE (f16), emits packed (src<<16)|ex_f16 and exact rowptrFine.
// ---------------------------------------------------------------------------
__global__ __launch_bounds__(256) void k_sort(const uint* __restrict__ binned,
                                              const int* __restrict__ bucketPtr,
                                              const float* __restrict__ sS,
                                              const float* __restrict__ sD,
                                              uint* __restrict__ srcEx,
                                              int* __restrict__ rowptrFine) {
    __shared__ ushort lsrc[BCAP];
    __shared__ ushort lex[BCAP];
    __shared__ int lhist[256], lcur[256], sc[256];
    __shared__ float ldsD[BNODES];
    int b = blockIdx.x, t = threadIdx.x;
    int beg = bucketPtr[b], end = bucketPtr[b + 1], n = end - beg;
    int node = b * BNODES + t;
    lhist[t] = 0;
    if (t < BNODES) ldsD[t] = (node < N_NODES) ? sD[node] : 0.f;
    __syncthreads();
    for (int i = t; i < n; i += 256)
        atomicAdd(&lhist[(binned[beg + i] >> 16) & 0xFF], 1);
    __syncthreads();
    int v = lhist[t]; sc[t] = v; __syncthreads();
    for (int off = 1; off < 256; off <<= 1) {
        int x = (t >= off) ? sc[t - off] : 0;
        __syncthreads(); sc[t] += x; __syncthreads();
    }
    int excl = sc[t] - v;
    lcur[t] = excl;
    if (t < BNODES && node < N_NODES) rowptrFine[node] = beg + excl;
    if (b == NBKT - 1 && t == 0) rowptrFine[N_NODES] = N_EDGES;
    __syncthreads();
    for (int i = t; i < n; i += 256) {
        uint w = binned[beg + i];
        int dl = (int)((w >> 16) & 0xFF);
        int s  = (int)(w & 0xFFFF);
        float e = sS[s] + ldsD[dl];
        e = e > 0.f ? e : SLOPE * e;
        ushort exb = f32_f16(__expf(e));
        int slot = atomicAdd(&lcur[dl], 1);
        lsrc[slot] = (ushort)s;
        lex[slot]  = exb;
    }
    __syncthreads();
    for (int i = t; i < n; i += 256)
        srcEx[beg + i] = ((uint)lsrc[i] << 16) | (uint)lex[i];
}

// ---------------------------------------------------------------------------
// K5: one wave per dst node, paired halves: lanes 0-31 process edge quads
// [8i,8i+4), lanes 32-63 [8i+4,8i+8); each lane covers 2 output dims via a
// packed-f16 dword gather (wave fetches 2 rows = 256B per instruction).
// den recomputed in-register; cross-half shfl_xor(32) combine; ELU + float2
// store by lanes 0-31.
// ---------------------------------------------------------------------------
__global__ __launch_bounds__(256) void k_aggc(const uint* __restrict__ zh32,
                                              const uint* __restrict__ srcEx,
                                              const int* __restrict__ rowptr,
                                              float* __restrict__ out) {
    int node = blockIdx.x * 4 + (threadIdx.x >> 6);
    int lane = threadIdx.x & 63;
    int half = lane >> 5, pl = lane & 31;
    int beg = rowptr[node], end = rowptr[node + 1];
    int cnt = end - beg;
    int nfull = cnt & ~7;

    float acc0 = 0.f, acc1 = 0.f, den = 0.f;
    for (int i = 0; i < nfull; i += 8) {
        int kb = beg + i + half * 4;
        uint w[4];
        #pragma unroll
        for (int u = 0; u < 4; ++u) w[u] = srcEx[kb + u];
        uint zp[4];
        #pragma unroll
        for (int u = 0; u < 4; ++u) zp[u] = zh32[((w[u] >> 16) << 5) + pl];
        #pragma unroll
        for (int u = 0; u < 4; ++u) {
            float ex = f16_f32((ushort)(w[u] & 0xFFFF));
            acc0 += ex * f16_f32((ushort)(zp[u] & 0xFFFF));
            acc1 += ex * f16_f32((ushort)(zp[u] >> 16));
            den  += ex;
        }
    }
    if (half == 0) {
        for (int k = beg + nfull; k < end; ++k) {
            uint w = srcEx[k];
            float ex = f16_f32((ushort)(w & 0xFFFF));
            uint zp = zh32[((w >> 16) << 5) + pl];
            acc0 += ex * f16_f32((ushort)(zp & 0xFFFF));
            acc1 += ex * f16_f32((ushort)(zp >> 16));
            den  += ex;
        }
    }
    acc0 += __shfl_xor(acc0, 32);
    acc1 += __shfl_xor(acc1, 32);
    den  += __shfl_xor(den, 32);

    if (half == 0) {
        float r0 = den > 0.f ? acc0 / den : 0.f;
        float r1 = den > 0.f ? acc1 / den : 0.f;
        r0 = r0 > 0.f ? r0 : expm1f(r0);
        r1 = r1 > 0.f ? r1 : expm1f(r1);
        ((float2*)out)[(((size_t)node) << 5) + pl] = make_float2(r0, r1);
    }
}

static inline char* alignup(char* p) {
    return (char*)(((uintptr_t)p + 63) & ~(uintptr_t)63);
}

extern "C" void kernel_launch(void* const* d_in, const int* in_sizes, int n_in,
                              void* d_out, int out_size, void* d_ws, size_t ws_size,
                              hipStream_t stream) {
    const float* h     = (const float*)d_in[0];
    const float* Wfc   = (const float*)d_in[1];
    const float* Wattn = (const float*)d_in[2];
    const int*   src   = (const int*)d_in[3];
    const int*   dst   = (const int*)d_in[4];
    float* out = (float*)d_out;

    // workspace layout (64B-aligned regions)
    char* p = (char*)d_ws;
    uint*   binned    = (uint*)p;             p = alignup(p + (size_t)N_EDGES * 4);
    uint*   srcEx     = (uint*)p;             p = alignup(p + (size_t)N_EDGES * 4);
    int*    rowptrF   = (int*)p;              p = alignup(p + (size_t)(N_NODES + 1) * 4);
    float*  sS        = (float*)p;            p = alignup(p + (size_t)N_NODES * 4);
    float*  sD        = (float*)p;            p = alignup(p + (size_t)N_NODES * 4);
    int*    gcount    = (int*)p;              p = alignup(p + NBKT * 4);
    int*    bucketPtr = (int*)p;              p = alignup(p + (NBKT + 1) * 4);
    int*    bucketCur = (int*)p;              p = alignup(p + NBKT * 4);
    ushort* Whi       = (ushort*)p;           p = alignup(p + OUT_DIM * IN_DIM * 2);
    ushort* Wlo       = (ushort*)p;           p = alignup(p + OUT_DIM * IN_DIM * 2);
    ushort* zh        = (ushort*)p;

    hipMemsetAsync(gcount, 0, NBKT * sizeof(int), stream);

    k_prep_hist<<<256 + 64, 256, 0, stream>>>(Wfc, Whi, Wlo, dst, gcount);
    k_gemm<<<N_NODES / 16, 64, 0, stream>>>(h, Whi, Wlo, Wattn, zh, sS, sD);
    k_scan<<<1, 256, 0, stream>>>(gcount, bucketPtr, bucketCur);
    k_bin<<<(N_EDGES + EPB - 1) / EPB, 256, 0, stream>>>(src, dst, bucketCur, binned);
    k_sort<<<NBKT, 256, 0, stream>>>(binned, bucketPtr, sS, sD, srcEx, rowptrF);
    k_aggc<<<N_NODES / 4, 256, 0, stream>>>((const uint*)zh, srcEx, rowptrF, out);
}